// Round 7
// baseline (47.389 us; speedup 1.0000x reference)
//
#include <hip/hip_runtime.h>
#include <hip/hip_bf16.h>

#define N 4096
#define D 768
#define LOG2E 1.44269504088896340736f
#define A_SCALE (20.0f * LOG2E)   // INV_T * log2(e): puts logits in base-2 domain
#define LN2 0.69314718055994530942f

typedef __attribute__((ext_vector_type(8))) short bf16x8;
typedef __attribute__((ext_vector_type(4))) float f32x4;

#define EXP2F(x) __builtin_amdgcn_exp2f(x)   // v_exp_f32: 2^x
#define LOG2F(x) __builtin_amdgcn_logf(x)    // v_log_f32: log2(x)

// global -> LDS direct DMA, 16B per lane, linear dest (wave base + lane*16)
#define GLDS16(g, l) __builtin_amdgcn_global_load_lds( \
    (const __attribute__((address_space(1))) void*)(g), \
    (__attribute__((address_space(3))) void*)(l), 16, 0, 0)

// ws layout (bytes):
//   [0,        6291456)  A bf16 (anchors * INV_T * log2e), N*D
//   [6291456, 12582912)  B bf16 (positives), N*D
//   [12582912,13107200)  partial[16][4096] float  (per colTile row sums of 2^s)
//   [13107200,13123584)  diagS[4096] float        (s2_jj, base-2 logit)
//   [13123584,13139968)  lastS[4096] float        (s2_{j,N-1})
//   [13139968,13140096)  blockSums[32] float

__device__ inline ushort f2bf(float x) {
    union { float f; unsigned u; } v; v.f = x;
    unsigned r = (v.u + 0x7fffu + ((v.u >> 16) & 1u)) >> 16;
    return (ushort)r;
}

__global__ void convert_kernel(const float* __restrict__ A, const float* __restrict__ B,
                               ushort* __restrict__ Abf, ushort* __restrict__ Bbf) {
    const int total = N * D / 4;
    int idx = blockIdx.x * blockDim.x + threadIdx.x;
    int stride = gridDim.x * blockDim.x;
    for (int i = idx; i < total; i += stride) {
        float4 a = ((const float4*)A)[i];
        float4 b = ((const float4*)B)[i];
        ushort4 av, bv;
        av.x = f2bf(a.x * A_SCALE); av.y = f2bf(a.y * A_SCALE);
        av.z = f2bf(a.z * A_SCALE); av.w = f2bf(a.w * A_SCALE);
        bv.x = f2bf(b.x); bv.y = f2bf(b.y); bv.z = f2bf(b.z); bv.w = f2bf(b.w);
        ((ushort4*)Abf)[i] = av;
        ((ushort4*)Bbf)[i] = bv;
    }
}

// 256x256 tile, BK=64, 8 waves (2M x 4N), per-wave 128x64 = acc[8][4].
// m201-style 8-phase schedule: per phase {ds_read subtile | stage 1 half-tile
// (2 GLDS) -> barrier -> lgkmcnt(0) -> 16 MFMA (setprio) -> barrier}; B-frags
// loaded whole-K-tile at the tile's first phase. Counted vmcnt(4) ONLY at the
// end of phases 4/8 (2 half-tiles stay in flight). Stage mapping per iter i
// (tiles t=2i,2i+1):  p0,p1: A_{t+1} -> slot1 | p2,p3: B_{t+2} -> slot0 |
// p4,p5: A_{t+2} -> slot0 | p6,p7: B_{t+3} -> slot1.  Each stage issues >=1
// barrier after the last read of its slot region (write-after-read safe);
// vmcnt(4)+barrier precedes first read of each tile (read-after-write safe).
// LDS linear (global_load_lds); bank conflicts killed by chunk-XOR swizzle on
// global source AND fragment ds_read (rule #21).
__global__ __launch_bounds__(512) void gemm_kernel(const ushort* __restrict__ Abf,
                                                   const ushort* __restrict__ Bbf,
                                                   float* __restrict__ partial,
                                                   float* __restrict__ diagS,
                                                   float* __restrict__ lastS) {
    __shared__ __align__(16) ushort As[2][256 * 64];  // 2 x 32 KB
    __shared__ __align__(16) ushort Bs[2][256 * 64];  // 2 x 32 KB
    __shared__ float rowsumL[4][256];                  // 4 KB

    const int t    = threadIdx.x;
    const int bCol = blockIdx.x;
    const int bRow = blockIdx.y;
    const int lane = t & 63;
    const int w    = t >> 6;      // wave 0..7
    const int wm   = w >> 2;      // wave M 0..1 (rows wm*128..+128)
    const int wn   = w & 3;       // wave N 0..3 (cols wn*64..+64)
    const int lr   = lane & 15;
    const int hi   = lane >> 4;

    // staging: thread t covers (row t>>3 within a 64-row round, 16B chunk t&7);
    // source chunk XOR-swizzled so linear LDS holds the swizzled image
    const int srow = t >> 3;            // 0..63
    const int sc   = t & 7;             // 0..7
    const int gcv  = sc ^ (srow & 7);   // swizzled global chunk

    f32x4 acc[8][4] = {};
    bf16x8 bfr[4][2];

#define STAGE_A(BUF, T, H) do {                                                        \
    GLDS16(Abf + (size_t)(bRow * 256 + (H) * 128 + srow) * D + (T) * 64 + gcv * 8,     \
           &As[BUF][((H) * 128 + w * 8) * 64]);                                        \
    GLDS16(Abf + (size_t)(bRow * 256 + (H) * 128 + 64 + srow) * D + (T) * 64 + gcv * 8,\
           &As[BUF][((H) * 128 + 64 + w * 8) * 64]);                                   \
} while (0)

#define STAGE_B(BUF, T, H) do {                                                        \
    GLDS16(Bbf + (size_t)(bCol * 256 + (H) * 128 + srow) * D + (T) * 64 + gcv * 8,     \
           &Bs[BUF][((H) * 128 + w * 8) * 64]);                                        \
    GLDS16(Bbf + (size_t)(bCol * 256 + (H) * 128 + 64 + srow) * D + (T) * 64 + gcv * 8,\
           &Bs[BUF][((H) * 128 + 64 + w * 8) * 64]);                                   \
} while (0)

#define LDA_FRAG(BUF, MF, KK) \
    (*(const bf16x8*)&As[BUF][(wm * 128 + (MF) * 16 + lr) * 64 + ((((KK) * 4 + hi) ^ (lr & 7)) * 8)])
#define LDB_FRAG(BUF, NF, KK) \
    (*(const bf16x8*)&Bs[BUF][(wn * 64 + (NF) * 16 + lr) * 64 + ((((KK) * 4 + hi) ^ (lr & 7)) * 8)])

#define VMCNT(NN) asm volatile("s_waitcnt vmcnt(" #NN ")" ::: "memory")

// One phase: quadrant Q (mf = 2Q,2Q+1) of the K-tile in BUF. FIRSTP: also load
// all B-frags (12 ds_reads -> template's lgkmcnt(8)). STCODE: stage one
// half-tile. CHKCODE: counted-vmcnt checkpoint (end of phases 4/8 only).
#define PHASE(BUF, Q, FIRSTP, STCODE, CHKCODE) do {                                    \
    if (FIRSTP) {                                                                      \
        _Pragma("unroll")                                                              \
        for (int nf = 0; nf < 4; ++nf)                                                 \
            _Pragma("unroll")                                                          \
            for (int kk = 0; kk < 2; ++kk)                                             \
                bfr[nf][kk] = LDB_FRAG(BUF, nf, kk);                                   \
    }                                                                                  \
    bf16x8 af[2][2];                                                                   \
    _Pragma("unroll")                                                                  \
    for (int j = 0; j < 2; ++j)                                                        \
        _Pragma("unroll")                                                              \
        for (int kk = 0; kk < 2; ++kk)                                                 \
            af[j][kk] = LDA_FRAG(BUF, 2 * (Q) + j, kk);                                \
    STCODE;                                                                            \
    if (FIRSTP) asm volatile("s_waitcnt lgkmcnt(8)" ::: "memory");                     \
    __builtin_amdgcn_s_barrier();                                                      \
    asm volatile("s_waitcnt lgkmcnt(0)" ::: "memory");                                 \
    __builtin_amdgcn_sched_barrier(0);                                                 \
    __builtin_amdgcn_s_setprio(1);                                                     \
    _Pragma("unroll")                                                                  \
    for (int kk = 0; kk < 2; ++kk)                                                     \
        _Pragma("unroll")                                                              \
        for (int j = 0; j < 2; ++j)                                                    \
            _Pragma("unroll")                                                          \
            for (int nf = 0; nf < 4; ++nf)                                             \
                acc[2 * (Q) + j][nf] = __builtin_amdgcn_mfma_f32_16x16x32_bf16(        \
                    af[j][kk], bfr[nf][kk], acc[2 * (Q) + j][nf], 0, 0, 0);            \
    __builtin_amdgcn_s_setprio(0);                                                     \
    CHKCODE;                                                                           \
    __builtin_amdgcn_s_barrier();                                                      \
    __builtin_amdgcn_sched_barrier(0);                                                 \
} while (0)

    // prologue: B_0, A_0 -> slot0; B_1 -> slot1 (12 loads/wave).
    // vmcnt(4): A_0+B_0 landed, B_1's 4 loads stay in flight.
    STAGE_B(0, 0, 0); STAGE_B(0, 0, 1);
    STAGE_A(0, 0, 0); STAGE_A(0, 0, 1);
    STAGE_B(1, 1, 0); STAGE_B(1, 1, 1);
    VMCNT(4);
    __builtin_amdgcn_s_barrier();
    __builtin_amdgcn_sched_barrier(0);

    // full iterations i=0..4 (tiles 0..9), staging tiles 1..11
    for (int i2 = 0; i2 < 5; ++i2) {
        const int tb = 2 * i2;
        PHASE(0, 0, 1, STAGE_A(1, tb + 1, 0), (void)0);
        PHASE(0, 1, 0, STAGE_A(1, tb + 1, 1), (void)0);
        PHASE(0, 2, 0, STAGE_B(0, tb + 2, 0), (void)0);
        PHASE(0, 3, 0, STAGE_B(0, tb + 2, 1), VMCNT(4));
        PHASE(1, 0, 1, STAGE_A(0, tb + 2, 0), (void)0);
        PHASE(1, 1, 0, STAGE_A(0, tb + 2, 1), (void)0);
        PHASE(1, 2, 0, STAGE_B(1, tb + 3, 0), (void)0);
        PHASE(1, 3, 0, STAGE_B(1, tb + 3, 1), VMCNT(4));
    }
    // last iteration (tiles 10,11): stage only A_11; full drain at mid checkpoint
    PHASE(0, 0, 1, STAGE_A(1, 11, 0), (void)0);
    PHASE(0, 1, 0, STAGE_A(1, 11, 1), (void)0);
    PHASE(0, 2, 0, (void)0, (void)0);
    PHASE(0, 3, 0, (void)0, VMCNT(0));
    PHASE(1, 0, 1, (void)0, (void)0);
    PHASE(1, 1, 0, (void)0, (void)0);
    PHASE(1, 2, 0, (void)0, (void)0);
    PHASE(1, 3, 0, (void)0, (void)0);

#undef PHASE
#undef VMCNT
#undef LDA_FRAG
#undef LDB_FRAG
#undef STAGE_A
#undef STAGE_B

    // C/D layout (m89): col = lane&15 (= lr), row = hi*4 + reg
    const int rifb = hi * 4;

    // diagonal capture: global row == global col (compile-time acc indices)
    if (bRow == bCol) {
        #pragma unroll
        for (int mf = 0; mf < 8; ++mf)
            #pragma unroll
            for (int nf = 0; nf < 4; ++nf)
                if (wm * 128 + mf * 16 == wn * 64 + nf * 16) {
                    #pragma unroll
                    for (int reg = 0; reg < 4; ++reg)
                        if (lr == rifb + reg)
                            diagS[bRow * 256 + wm * 128 + mf * 16 + rifb + reg] = acc[mf][nf][reg];
                }
    }

    // last-column capture: col N-1 -> bCol==15, wn==3, nf==3, lr==15
    if (bCol == (N / 256 - 1) && wn == 3 && lr == 15) {
        #pragma unroll
        for (int mf = 0; mf < 8; ++mf)
            #pragma unroll
            for (int reg = 0; reg < 4; ++reg)
                lastS[bRow * 256 + wm * 128 + mf * 16 + rifb + reg] = acc[mf][3][reg];
    }

    // 2^s over the tile, row-sum across the wave's 64 columns
    #pragma unroll
    for (int mf = 0; mf < 8; ++mf) {
        #pragma unroll
        for (int reg = 0; reg < 4; ++reg) {
            float s = EXP2F(acc[mf][0][reg]) + EXP2F(acc[mf][1][reg]) +
                      EXP2F(acc[mf][2][reg]) + EXP2F(acc[mf][3][reg]);
            s += __shfl_xor(s, 1);
            s += __shfl_xor(s, 2);
            s += __shfl_xor(s, 4);
            s += __shfl_xor(s, 8);
            if (lr == 0) rowsumL[wn][wm * 128 + mf * 16 + rifb + reg] = s;
        }
    }
    __syncthreads();
    if (t < 256)
        partial[(size_t)bCol * N + bRow * 256 + t] =
            rowsumL[0][t] + rowsumL[1][t] + rowsumL[2][t] + rowsumL[3][t];
}

__global__ void rowloss_kernel(const float* __restrict__ partial, const float* __restrict__ diagS,
                               const float* __restrict__ lastS, float* __restrict__ blockSums) {
    const int j = blockIdx.x * 128 + threadIdx.x;
    float rs = 0.0f;
    #pragma unroll
    for (int tI = 0; tI < 16; ++tI) rs += partial[(size_t)tI * N + j];
    float denom = rs + EXP2F(diagS[j]);
    float lossj = LN2 * (LOG2F(denom) - lastS[j]);
    #pragma unroll
    for (int off = 1; off < 64; off <<= 1) lossj += __shfl_xor(lossj, off);
    __shared__ float ws2[2];
    if ((threadIdx.x & 63) == 0) ws2[threadIdx.x >> 6] = lossj;
    __syncthreads();
    if (threadIdx.x == 0) blockSums[blockIdx.x] = ws2[0] + ws2[1];
}

__global__ void final_kernel(const float* __restrict__ blockSums, float* __restrict__ out) {
    float v = (threadIdx.x < 32) ? blockSums[threadIdx.x] : 0.0f;
    #pragma unroll
    for (int off = 1; off < 32; off <<= 1) v += __shfl_xor(v, off);
    if (threadIdx.x == 0) out[0] = v;
}

extern "C" void kernel_launch(void* const* d_in, const int* in_sizes, int n_in,
                              void* d_out, int out_size, void* d_ws, size_t ws_size,
                              hipStream_t stream) {
    const float* A = (const float*)d_in[0];
    const float* B = (const float*)d_in[1];
    float* out = (float*)d_out;
    char* ws = (char*)d_ws;

    ushort* Abf      = (ushort*)(ws);
    ushort* Bbf      = (ushort*)(ws + 6291456);
    float*  partial  = (float*)(ws + 12582912);
    float*  diagS    = (float*)(ws + 13107200);
    float*  lastS    = (float*)(ws + 13123584);
    float*  blockSums= (float*)(ws + 13139968);

    convert_kernel<<<1024, 256, 0, stream>>>(A, B, Abf, Bbf);
    gemm_kernel<<<dim3(16, 16), 512, 0, stream>>>(Abf, Bbf, partial, diagS, lastS);
    rowloss_kernel<<<32, 128, 0, stream>>>(partial, diagS, lastS, blockSums);
    final_kernel<<<1, 64, 0, stream>>>(blockSums, out);
}